// Round 1
// baseline (3229.005 us; speedup 1.0000x reference)
//
#include <hip/hip_runtime.h>
#include <hip/hip_bf16.h>
#include <math.h>

#define D_DIM 512
#define NSEQ  4096
#define BATCH 4
#define SCALE 0.125f   // (D/HEAD_NUMB)^-0.5 = 64^-0.5

// ============================================================
// Kernel 1: QKV projection  qkv[m][e] = sum_d x[m][d]*W[e][d] + b[e]
// m in [0,16384), e in [0,1536). Writes bf16 Q|K|V into workspace.
// ============================================================
#define BM  128
#define BN  128
#define BKC 32
#define GS_STRIDE (BM + 4)   // LDS row stride (floats); 132*4B keeps 16B align

__global__ __launch_bounds__(256) void qkv_gemm(
    const float* __restrict__ x, const float* __restrict__ W,
    const float* __restrict__ bias, __hip_bfloat16* __restrict__ qkv)
{
    __shared__ float Xs[BKC][GS_STRIDE];   // [k][m] transposed
    __shared__ float Ws[BKC][GS_STRIDE];   // [k][n] transposed
    const int m0 = blockIdx.x * BM;
    const int n0 = blockIdx.y * BN;
    const int t  = threadIdx.x;
    const int tx = t & 15, ty = t >> 4;

    float acc[8][8];
#pragma unroll
    for (int i = 0; i < 8; i++)
#pragma unroll
        for (int j = 0; j < 8; j++) acc[i][j] = 0.f;

    for (int k0 = 0; k0 < D_DIM; k0 += BKC) {
        __syncthreads();
#pragma unroll
        for (int i = 0; i < 4; i++) {
            int f   = t + i * 256;     // 0..1023 float4 slots
            int row = f >> 3;          // 0..127
            int kq  = f & 7;           // float4 within 32-k strip
            float4 vx = *(const float4*)(x + (size_t)(m0 + row) * D_DIM + k0 + 4 * kq);
            Xs[4*kq+0][row] = vx.x; Xs[4*kq+1][row] = vx.y;
            Xs[4*kq+2][row] = vx.z; Xs[4*kq+3][row] = vx.w;
            float4 vw = *(const float4*)(W + (size_t)(n0 + row) * D_DIM + k0 + 4 * kq);
            Ws[4*kq+0][row] = vw.x; Ws[4*kq+1][row] = vw.y;
            Ws[4*kq+2][row] = vw.z; Ws[4*kq+3][row] = vw.w;
        }
        __syncthreads();
#pragma unroll
        for (int k = 0; k < BKC; k++) {
            float a[8], b[8];
            *(float4*)&a[0] = *(const float4*)&Xs[k][ty * 4];
            *(float4*)&a[4] = *(const float4*)&Xs[k][64 + ty * 4];
            *(float4*)&b[0] = *(const float4*)&Ws[k][tx * 4];
            *(float4*)&b[4] = *(const float4*)&Ws[k][64 + tx * 4];
#pragma unroll
            for (int i = 0; i < 8; i++)
#pragma unroll
                for (int j = 0; j < 8; j++)
                    acc[i][j] += a[i] * b[j];
        }
    }

    const size_t seg_sz = (size_t)BATCH * NSEQ * D_DIM;  // 8388608 elems per Q/K/V
#pragma unroll
    for (int i = 0; i < 8; i++) {
        int m = m0 + ((i < 4) ? (ty * 4 + i) : (64 + ty * 4 + i - 4));
#pragma unroll
        for (int jh = 0; jh < 2; jh++) {
            int c0 = n0 + ((jh == 0) ? (tx * 4) : (64 + tx * 4));
            float4 b4 = *(const float4*)(bias + c0);
            float v0 = acc[i][jh*4+0] + b4.x;
            float v1 = acc[i][jh*4+1] + b4.y;
            float v2 = acc[i][jh*4+2] + b4.z;
            float v3 = acc[i][jh*4+3] + b4.w;
            int seg = c0 >> 9;       // 0:Q 1:K 2:V (BN=128 nests in 512 bounds)
            int eo  = c0 & 511;
            __hip_bfloat16 h[4];
            h[0] = __float2bfloat16(v0); h[1] = __float2bfloat16(v1);
            h[2] = __float2bfloat16(v2); h[3] = __float2bfloat16(v3);
            *(uint2*)(qkv + (size_t)seg * seg_sz + (size_t)m * D_DIM + eo) = *(uint2*)h;
        }
    }
}

// ============================================================
// Kernel 2: flash attention (fp32 compute, bf16 operand storage)
// grid (NSEQ/BQ, BATCH), 512 threads
// ============================================================
#define BQ 64
#define BK 64
#define DC 64     // d-chunk for score GEMM
#define VC 128    // d-chunk for PV
#define QT_STRIDE (BQ + 4)   // 68 floats -> 16B aligned rows
#define PS_STRIDE (BK + 4)
#define VS_STRIDE (VC + 4)

__global__ __launch_bounds__(512) void flash_attn(
    const __hip_bfloat16* __restrict__ qkv, float* __restrict__ out)
{
    __shared__ float Qt[DC][QT_STRIDE];   // [d][i]
    __shared__ float Kt[DC][QT_STRIDE];   // [d][j]
    __shared__ float Ps[BQ][PS_STRIDE];   // scores -> probs
    __shared__ float Vs[BK][VS_STRIDE];   // [j][d-chunk]
    __shared__ float m_state[BQ], l_state[BQ], alpha_s[BQ];

    const int b  = blockIdx.y;
    const int q0 = blockIdx.x * BQ;
    const int t  = threadIdx.x;
    const size_t seg  = (size_t)BATCH * NSEQ * D_DIM;
    const size_t base = (size_t)b * NSEQ * D_DIM;
    const __hip_bfloat16* Qg = qkv + base;
    const __hip_bfloat16* Kg = qkv + seg + base;
    const __hip_bfloat16* Vg = qkv + 2 * seg + base;

    const int tx = t & 15;       // score: 4-col group | PV: 8-float d group
    const int ty = t >> 4;       // 2-row group (0..31)
    const int st_row = t >> 3;   // staging row 0..63
    const int st_c8  = t & 7;    // staging 8-elem chunk

    float o_acc[2][4][8];        // [row][VC chunk][d] fp32 accumulators
#pragma unroll
    for (int r = 0; r < 2; r++)
#pragma unroll
        for (int c = 0; c < 4; c++)
#pragma unroll
            for (int d = 0; d < 8; d++) o_acc[r][c][d] = 0.f;

    if (t < BQ) { m_state[t] = -__builtin_inff(); l_state[t] = 0.f; }

    for (int kt = 0; kt < NSEQ; kt += BK) {
        // ---------------- scores S = Q K^T ----------------
        float s_acc[2][4];
#pragma unroll
        for (int r = 0; r < 2; r++)
#pragma unroll
            for (int c = 0; c < 4; c++) s_acc[r][c] = 0.f;

        for (int dc = 0; dc < D_DIM; dc += DC) {
            __syncthreads();   // Qt/Kt (and Ps/alpha) safe: prior readers done
            {
                union { uint4 u; __hip_bfloat16 h[8]; } qv, kv;
                qv.u = *(const uint4*)(Qg + (size_t)(q0 + st_row) * D_DIM + dc + 8 * st_c8);
                kv.u = *(const uint4*)(Kg + (size_t)(kt + st_row) * D_DIM + dc + 8 * st_c8);
#pragma unroll
                for (int c = 0; c < 8; c++) {
                    Qt[8 * st_c8 + c][st_row] = __bfloat162float(qv.h[c]);
                    Kt[8 * st_c8 + c][st_row] = __bfloat162float(kv.h[c]);
                }
            }
            __syncthreads();
#pragma unroll 8
            for (int d = 0; d < DC; d++) {
                float2 a  = *(const float2*)&Qt[d][2 * ty];
                float4 bv = *(const float4*)&Kt[d][4 * tx];
                s_acc[0][0] += a.x * bv.x; s_acc[0][1] += a.x * bv.y;
                s_acc[0][2] += a.x * bv.z; s_acc[0][3] += a.x * bv.w;
                s_acc[1][0] += a.y * bv.x; s_acc[1][1] += a.y * bv.y;
                s_acc[1][2] += a.y * bv.z; s_acc[1][3] += a.y * bv.w;
            }
        }
#pragma unroll
        for (int j = 0; j < 4; j++) {
            Ps[2 * ty][4 * tx + j]     = s_acc[0][j] * SCALE;
            Ps[2 * ty + 1][4 * tx + j] = s_acc[1][j] * SCALE;
        }
        __syncthreads();
        // ---------------- online softmax (8 threads / row) ----------------
        {
            int row = st_row, sub = st_c8;
            float4 v0 = *(const float4*)&Ps[row][8 * sub];
            float4 v1 = *(const float4*)&Ps[row][8 * sub + 4];
            float mx = fmaxf(fmaxf(fmaxf(v0.x, v0.y), fmaxf(v0.z, v0.w)),
                             fmaxf(fmaxf(v1.x, v1.y), fmaxf(v1.z, v1.w)));
            mx = fmaxf(mx, __shfl_xor(mx, 1));
            mx = fmaxf(mx, __shfl_xor(mx, 2));
            mx = fmaxf(mx, __shfl_xor(mx, 4));
            float m_old = m_state[row];
            float m_new = fmaxf(m_old, mx);
            float p0 = __expf(v0.x - m_new), p1 = __expf(v0.y - m_new);
            float p2 = __expf(v0.z - m_new), p3 = __expf(v0.w - m_new);
            float p4 = __expf(v1.x - m_new), p5 = __expf(v1.y - m_new);
            float p6 = __expf(v1.z - m_new), p7 = __expf(v1.w - m_new);
            float s = p0 + p1 + p2 + p3 + p4 + p5 + p6 + p7;
            s += __shfl_xor(s, 1); s += __shfl_xor(s, 2); s += __shfl_xor(s, 4);
            *(float4*)&Ps[row][8 * sub]     = make_float4(p0, p1, p2, p3);
            *(float4*)&Ps[row][8 * sub + 4] = make_float4(p4, p5, p6, p7);
            if (sub == 0) {
                float al = __expf(m_old - m_new);
                alpha_s[row] = al;
                m_state[row] = m_new;
                l_state[row] = l_state[row] * al + s;
            }
        }
        __syncthreads();
        // rescale O accumulators
        float al0 = alpha_s[2 * ty], al1 = alpha_s[2 * ty + 1];
#pragma unroll
        for (int c = 0; c < 4; c++)
#pragma unroll
            for (int dd = 0; dd < 8; dd++) {
                o_acc[0][c][dd] *= al0;
                o_acc[1][c][dd] *= al1;
            }
        // ---------------- O += P V ----------------
        for (int vc = 0; vc < 4; vc++) {
            __syncthreads();   // Vs reuse guard
            {
                const __hip_bfloat16* vp =
                    Vg + (size_t)(kt + st_row) * D_DIM + vc * VC + 16 * st_c8;
                union { uint4 u; __hip_bfloat16 h[8]; } a0, a1;
                a0.u = *(const uint4*)vp;
                a1.u = *(const uint4*)(vp + 8);
#pragma unroll
                for (int c = 0; c < 8; c++) {
                    Vs[st_row][16 * st_c8 + c]     = __bfloat162float(a0.h[c]);
                    Vs[st_row][16 * st_c8 + 8 + c] = __bfloat162float(a1.h[c]);
                }
            }
            __syncthreads();
#pragma unroll 4
            for (int j = 0; j < BK; j++) {
                float pr0 = Ps[2 * ty][j];
                float pr1 = Ps[2 * ty + 1][j];
                float4 u0 = *(const float4*)&Vs[j][8 * tx];
                float4 u1 = *(const float4*)&Vs[j][8 * tx + 4];
                o_acc[0][vc][0] += pr0 * u0.x; o_acc[0][vc][1] += pr0 * u0.y;
                o_acc[0][vc][2] += pr0 * u0.z; o_acc[0][vc][3] += pr0 * u0.w;
                o_acc[0][vc][4] += pr0 * u1.x; o_acc[0][vc][5] += pr0 * u1.y;
                o_acc[0][vc][6] += pr0 * u1.z; o_acc[0][vc][7] += pr0 * u1.w;
                o_acc[1][vc][0] += pr1 * u0.x; o_acc[1][vc][1] += pr1 * u0.y;
                o_acc[1][vc][2] += pr1 * u0.z; o_acc[1][vc][3] += pr1 * u0.w;
                o_acc[1][vc][4] += pr1 * u1.x; o_acc[1][vc][5] += pr1 * u1.y;
                o_acc[1][vc][6] += pr1 * u1.z; o_acc[1][vc][7] += pr1 * u1.w;
            }
        }
    }
    __syncthreads();
    // ---------------- epilogue: O / l ----------------
    float inv0 = 1.f / l_state[2 * ty];
    float inv1 = 1.f / l_state[2 * ty + 1];
    const int orow0 = q0 + 2 * ty, orow1 = orow0 + 1;
#pragma unroll
    for (int vc = 0; vc < 4; vc++) {
#pragma unroll
        for (int h = 0; h < 2; h++) {
            float4 w0, w1;
            w0.x = o_acc[0][vc][4*h+0] * inv0; w0.y = o_acc[0][vc][4*h+1] * inv0;
            w0.z = o_acc[0][vc][4*h+2] * inv0; w0.w = o_acc[0][vc][4*h+3] * inv0;
            w1.x = o_acc[1][vc][4*h+0] * inv1; w1.y = o_acc[1][vc][4*h+1] * inv1;
            w1.z = o_acc[1][vc][4*h+2] * inv1; w1.w = o_acc[1][vc][4*h+3] * inv1;
            *(float4*)(out + base + (size_t)orow0 * D_DIM + vc * VC + 8 * tx + 4 * h) = w0;
            *(float4*)(out + base + (size_t)orow1 * D_DIM + vc * VC + 8 * tx + 4 * h) = w1;
        }
    }
}

extern "C" void kernel_launch(void* const* d_in, const int* in_sizes, int n_in,
                              void* d_out, int out_size, void* d_ws, size_t ws_size,
                              hipStream_t stream)
{
    (void)in_sizes; (void)n_in; (void)out_size; (void)ws_size;
    const float* x    = (const float*)d_in[0];
    const float* W    = (const float*)d_in[1];
    const float* bias = (const float*)d_in[2];
    float* out = (float*)d_out;
    __hip_bfloat16* qkv = (__hip_bfloat16*)d_ws;   // 3 * 16.78M bf16 = 50.3 MB

    dim3 g1((BATCH * NSEQ) / BM, (3 * D_DIM) / BN);   // (128, 12)
    qkv_gemm<<<g1, 256, 0, stream>>>(x, W, bias, qkv);

    dim3 g2(NSEQ / BQ, BATCH);                        // (64, 4)
    flash_attn<<<g2, 512, 0, stream>>>(qkv, out);
}

// Round 2
// 357.964 us; speedup vs baseline: 9.0205x; 9.0205x over previous
//
#include <hip/hip_runtime.h>
#include <hip/hip_bf16.h>

#define D_DIM 512
#define NSEQ  4096
#define BATCH 4
#define SCALE 0.125f

typedef __attribute__((ext_vector_type(8)))  short short8;
typedef __attribute__((ext_vector_type(16))) float floatx16;

__device__ __forceinline__ unsigned short f2bf(float f) {
    __hip_bfloat16 h = __float2bfloat16(f);
    return *reinterpret_cast<unsigned short*>(&h);
}

__device__ __forceinline__ floatx16 mfma_bf16(short8 a, short8 b, floatx16 c) {
    return __builtin_amdgcn_mfma_f32_32x32x16_bf16(a, b, c, 0, 0, 0);
}

// ============================================================
// Kernel 1: QKV projection, bf16 MFMA.
// qkv[m][e] = sum_d x[m][d] W[e][d] + b[e]
// Outputs: qs = (q+b)*0.125 [tok][d], kk = k+b [tok][d], vT = (v+b) [b][d][tok]
// ============================================================
#define K1_STRIDE 40   // elems; 80 B rows (16B aligned)

__global__ __launch_bounds__(256, 2) void qkv_gemm(
    const float* __restrict__ x, const float* __restrict__ W,
    const float* __restrict__ bias,
    unsigned short* __restrict__ qs, unsigned short* __restrict__ kk,
    unsigned short* __restrict__ vT)
{
    __shared__ __align__(16) unsigned short Xs[128 * K1_STRIDE];
    __shared__ __align__(16) unsigned short Ws[128 * K1_STRIDE];

    const int t = threadIdx.x;
    const int lane = t & 63, w = t >> 6;
    const int l31 = lane & 31, lh = lane >> 5;
    const int wm = w >> 1, we = w & 1;
    const int m0 = blockIdx.x * 128;
    const int n0 = blockIdx.y * 128;

    floatx16 a00, a01, a10, a11;
#pragma unroll
    for (int r = 0; r < 16; r++) { a00[r] = 0.f; a01[r] = 0.f; a10[r] = 0.f; a11[r] = 0.f; }

    for (int kc = 0; kc < 16; kc++) {
        const int k0 = kc * 32;
        __syncthreads();
#pragma unroll
        for (int p = 0; p < 4; p++) {
            int id = t + p * 256;
            int row = id >> 3, kq = id & 7;
            float4 xv = *(const float4*)(x + (size_t)(m0 + row) * D_DIM + k0 + 4 * kq);
            ushort4 hx; hx.x = f2bf(xv.x); hx.y = f2bf(xv.y); hx.z = f2bf(xv.z); hx.w = f2bf(xv.w);
            *(ushort4*)&Xs[row * K1_STRIDE + 4 * kq] = hx;
            float4 wv = *(const float4*)(W + (size_t)(n0 + row) * D_DIM + k0 + 4 * kq);
            ushort4 hw; hw.x = f2bf(wv.x); hw.y = f2bf(wv.y); hw.z = f2bf(wv.z); hw.w = f2bf(wv.w);
            *(ushort4*)&Ws[row * K1_STRIDE + 4 * kq] = hw;
        }
        __syncthreads();
#pragma unroll
        for (int ks = 0; ks < 2; ks++) {
            const int co = ks * 16 + lh * 8;
            short8 fa0 = *(const short8*)&Xs[(wm * 64 + l31) * K1_STRIDE + co];
            short8 fa1 = *(const short8*)&Xs[(wm * 64 + 32 + l31) * K1_STRIDE + co];
            short8 fb0 = *(const short8*)&Ws[(we * 64 + l31) * K1_STRIDE + co];
            short8 fb1 = *(const short8*)&Ws[(we * 64 + 32 + l31) * K1_STRIDE + co];
            a00 = mfma_bf16(fa0, fb0, a00);
            a01 = mfma_bf16(fa0, fb1, a01);
            a10 = mfma_bf16(fa1, fb0, a10);
            a11 = mfma_bf16(fa1, fb1, a11);
        }
    }

    // epilogue: C/D layout col = lane&31, row = (r&3)+8*(r>>2)+4*lh
#pragma unroll
    for (int jt = 0; jt < 2; jt++) {
        const int e = n0 + we * 64 + jt * 32 + l31;
        const float bv = bias[e];
#pragma unroll
        for (int it = 0; it < 2; it++) {
            const int mb = m0 + wm * 64 + it * 32;
            const floatx16& av = (it == 0) ? ((jt == 0) ? a00 : a01)
                                           : ((jt == 0) ? a10 : a11);
            if (e < 512) {
#pragma unroll
                for (int r = 0; r < 16; r++) {
                    int m = mb + (r & 3) + 8 * (r >> 2) + 4 * lh;
                    qs[(size_t)m * D_DIM + e] = f2bf((av[r] + bv) * SCALE);
                }
            } else if (e < 1024) {
#pragma unroll
                for (int r = 0; r < 16; r++) {
                    int m = mb + (r & 3) + 8 * (r >> 2) + 4 * lh;
                    kk[(size_t)m * D_DIM + (e - 512)] = f2bf(av[r] + bv);
                }
            } else {
                const int d = e - 1024;
#pragma unroll
                for (int q = 0; q < 4; q++) {
                    int mq = mb + 8 * q + 4 * lh;          // 4 consecutive tokens
                    int bb = mq >> 12; int tok = mq & 4095;
                    ushort4 hv;
                    hv.x = f2bf(av[4 * q + 0] + bv); hv.y = f2bf(av[4 * q + 1] + bv);
                    hv.z = f2bf(av[4 * q + 2] + bv); hv.w = f2bf(av[4 * q + 3] + bv);
                    *(ushort4*)&vT[((size_t)bb * 512 + d) * 4096 + tok] = hv;
                }
            }
        }
    }
}

// ============================================================
// Kernel 2: flash attention, bf16 MFMA.
// 512 threads / 8 waves. BQ=64, BK=256. S computed transposed (K·Q^T) so
// softmax row-stats live on lane&31. Waves: wi=w&1 (i-tile), wjj=w>>1
// (j-quarter) for QK^T; wave w owns d-chunk w*64 for PV.
// ============================================================
#define FA_BQ 64
#define FA_BK 256
#define FA_DC 128
#define QC_STR 136
#define KC_STR 136
#define P_STR  264
#define VT_STR 72

__global__ __launch_bounds__(512, 2) void flash_attn(
    const unsigned short* __restrict__ qs, const unsigned short* __restrict__ kk,
    const unsigned short* __restrict__ vT, float* __restrict__ out)
{
    __shared__ __align__(16) unsigned char smem[123392];
    unsigned short* Qc = (unsigned short*)(smem);            // [64][136]  (union w/ Vt)
    unsigned short* Kc = (unsigned short*)(smem + 17408);    // [256][136] (union w/ Vt)
    unsigned short* Vt = (unsigned short*)(smem);            // [512][72]
    unsigned short* P  = (unsigned short*)(smem + 87040);    // [64][264]
    float* pmax    = (float*)(smem + 120832);                // [64][4]
    float* psum    = (float*)(smem + 121856);                // [64][4]
    float* alpha_s = (float*)(smem + 122880);                // [64]
    float* l_s     = (float*)(smem + 123136);                // [64]

    const int t = threadIdx.x;
    const int lane = t & 63, w = t >> 6;
    const int l31 = lane & 31, lh = lane >> 5;
    const int wi = w & 1, wjj = w >> 1;
    const int b  = blockIdx.y;
    const int q0 = blockIdx.x * FA_BQ;
    const size_t qbase = ((size_t)b * NSEQ + q0) * D_DIM;
    const size_t kbase = (size_t)b * NSEQ * D_DIM;
    const size_t vbase = (size_t)b * D_DIM * NSEQ;           // vT[b][d][tok]

    const int i_my = wi * 32 + l31;                          // softmax row (0..63)

    floatx16 o00, o01, o10, o11;                             // o[it][dtt]
#pragma unroll
    for (int r = 0; r < 16; r++) { o00[r] = 0.f; o01[r] = 0.f; o10[r] = 0.f; o11[r] = 0.f; }
    float m_st = -__builtin_inff(), l_st = 0.f;

    for (int kt = 0; kt < NSEQ; kt += FA_BK) {
        // ---------------- S^T = K Q^T ----------------
        floatx16 s0, s1;
#pragma unroll
        for (int r = 0; r < 16; r++) { s0[r] = 0.f; s1[r] = 0.f; }

        for (int dc = 0; dc < D_DIM; dc += FA_DC) {
            __syncthreads();
#pragma unroll
            for (int p = 0; p < 2; p++) {                    // Qc: 64 rows x 128 d
                int id = t + p * 512;
                int row = id >> 4, c8 = id & 15;
                uint4 v = *(const uint4*)(qs + qbase + (size_t)row * D_DIM + dc + c8 * 8);
                *(uint4*)&Qc[row * QC_STR + c8 * 8] = v;
            }
#pragma unroll
            for (int p = 0; p < 8; p++) {                    // Kc: 256 rows x 128 d
                int id = t + p * 512;
                int row = id >> 4, c8 = id & 15;
                uint4 v = *(const uint4*)(kk + kbase + (size_t)(kt + row) * D_DIM + dc + c8 * 8);
                *(uint4*)&Kc[row * KC_STR + c8 * 8] = v;
            }
            __syncthreads();
            const unsigned short* kr0 = &Kc[(wjj * 64 + l31) * KC_STR];
            const unsigned short* kr1 = kr0 + 32 * KC_STR;
            const unsigned short* qr  = &Qc[i_my * QC_STR];
#pragma unroll
            for (int ks = 0; ks < 8; ks++) {
                const int co = ks * 16 + lh * 8;
                short8 fa0 = *(const short8*)(kr0 + co);
                short8 fa1 = *(const short8*)(kr1 + co);
                short8 fb  = *(const short8*)(qr + co);
                s0 = mfma_bf16(fa0, fb, s0);
                s1 = mfma_bf16(fa1, fb, s1);
            }
        }

        // ---------------- online softmax (S^T: col=i on lane&31, rows=j) ----
        float mx = -__builtin_inff();
#pragma unroll
        for (int r = 0; r < 16; r++) mx = fmaxf(mx, fmaxf(s0[r], s1[r]));
        mx = fmaxf(mx, __shfl_xor(mx, 32));
        if (lh == 0) pmax[i_my * 4 + wjj] = mx;
        __syncthreads();
        float4 pm = *(float4*)&pmax[i_my * 4];
        const float m_new = fmaxf(m_st, fmaxf(fmaxf(pm.x, pm.y), fmaxf(pm.z, pm.w)));
        const float alpha = __expf(m_st - m_new);
        m_st = m_new;

        float sum = 0.f;
        {
            const int prow = i_my * P_STR;
#pragma unroll
            for (int q = 0; q < 4; q++) {
                float p0 = __expf(s0[4*q+0] - m_new), p1 = __expf(s0[4*q+1] - m_new);
                float p2 = __expf(s0[4*q+2] - m_new), p3 = __expf(s0[4*q+3] - m_new);
                sum += (p0 + p1) + (p2 + p3);
                ushort4 h; h.x = f2bf(p0); h.y = f2bf(p1); h.z = f2bf(p2); h.w = f2bf(p3);
                *(ushort4*)&P[prow + (wjj*2+0)*32 + 8*q + 4*lh] = h;
            }
#pragma unroll
            for (int q = 0; q < 4; q++) {
                float p0 = __expf(s1[4*q+0] - m_new), p1 = __expf(s1[4*q+1] - m_new);
                float p2 = __expf(s1[4*q+2] - m_new), p3 = __expf(s1[4*q+3] - m_new);
                sum += (p0 + p1) + (p2 + p3);
                ushort4 h; h.x = f2bf(p0); h.y = f2bf(p1); h.z = f2bf(p2); h.w = f2bf(p3);
                *(ushort4*)&P[prow + (wjj*2+1)*32 + 8*q + 4*lh] = h;
            }
        }
        sum += __shfl_xor(sum, 32);
        if (lh == 0) psum[i_my * 4 + wjj] = sum;
        if (lh == 0 && wjj == 0) alpha_s[i_my] = alpha;
        __syncthreads();
        float4 ps = *(float4*)&psum[i_my * 4];
        l_st = l_st * alpha + ((ps.x + ps.y) + (ps.z + ps.w));

        // ---------------- rescale O by alpha (skip if all == 1) -------------
        float av[2][16];
        bool ch = false;
#pragma unroll
        for (int it = 0; it < 2; it++)
#pragma unroll
            for (int q = 0; q < 4; q++) {
                float4 a4 = *(float4*)&alpha_s[it * 32 + 8 * q + 4 * lh];
                av[it][4*q+0] = a4.x; av[it][4*q+1] = a4.y;
                av[it][4*q+2] = a4.z; av[it][4*q+3] = a4.w;
                ch = ch || (a4.x != 1.f) || (a4.y != 1.f) || (a4.z != 1.f) || (a4.w != 1.f);
            }
        if (__any(ch)) {
#pragma unroll
            for (int r = 0; r < 16; r++) {
                o00[r] *= av[0][r]; o01[r] *= av[0][r];
                o10[r] *= av[1][r]; o11[r] *= av[1][r];
            }
        }

        // ---------------- O += P V  (wave w owns d-chunk w*64) --------------
        for (int jc = 0; jc < 4; jc++) {
            __syncthreads();
#pragma unroll
            for (int p = 0; p < 8; p++) {                    // Vt: 512 d x 64 j
                int id = t + p * 512;
                int d = id >> 3, c8 = id & 7;
                uint4 v = *(const uint4*)(vT + vbase + (size_t)d * NSEQ + kt + jc * 64 + c8 * 8);
                *(uint4*)&Vt[d * VT_STR + c8 * 8] = v;
            }
            __syncthreads();
            const unsigned short* pr0 = &P[l31 * P_STR + jc * 64];
            const unsigned short* pr1 = &P[(32 + l31) * P_STR + jc * 64];
            const unsigned short* vr0 = &Vt[(w * 64 + l31) * VT_STR];
            const unsigned short* vr1 = vr0 + 32 * VT_STR;
#pragma unroll
            for (int js = 0; js < 4; js++) {
                const int co = js * 16 + lh * 8;
                short8 pa0 = *(const short8*)(pr0 + co);
                short8 pa1 = *(const short8*)(pr1 + co);
                short8 vb0 = *(const short8*)(vr0 + co);
                short8 vb1 = *(const short8*)(vr1 + co);
                o00 = mfma_bf16(pa0, vb0, o00);
                o01 = mfma_bf16(pa0, vb1, o01);
                o10 = mfma_bf16(pa1, vb0, o10);
                o11 = mfma_bf16(pa1, vb1, o11);
            }
        }
    }

    // ---------------- epilogue: O / l ----------------
    if (lh == 0 && wjj == 0) l_s[i_my] = l_st;
    __syncthreads();
    float iv[2][16];
#pragma unroll
    for (int it = 0; it < 2; it++)
#pragma unroll
        for (int q = 0; q < 4; q++) {
            float4 l4 = *(float4*)&l_s[it * 32 + 8 * q + 4 * lh];
            iv[it][4*q+0] = 1.f / l4.x; iv[it][4*q+1] = 1.f / l4.y;
            iv[it][4*q+2] = 1.f / l4.z; iv[it][4*q+3] = 1.f / l4.w;
        }
#pragma unroll
    for (int it = 0; it < 2; it++) {
        const floatx16& oa = (it == 0) ? o00 : o10;
        const floatx16& ob = (it == 0) ? o01 : o11;
#pragma unroll
        for (int r = 0; r < 16; r++) {
            const int i = it * 32 + (r & 3) + 8 * (r >> 2) + 4 * lh;
            const size_t rowb = ((size_t)b * NSEQ + q0 + i) * D_DIM;
            out[rowb + w * 64 + l31]      = oa[r] * iv[it][r];
            out[rowb + w * 64 + 32 + l31] = ob[r] * iv[it][r];
        }
    }
}

extern "C" void kernel_launch(void* const* d_in, const int* in_sizes, int n_in,
                              void* d_out, int out_size, void* d_ws, size_t ws_size,
                              hipStream_t stream)
{
    (void)in_sizes; (void)n_in; (void)out_size; (void)ws_size;
    const float* x    = (const float*)d_in[0];
    const float* W    = (const float*)d_in[1];
    const float* bias = (const float*)d_in[2];
    float* out = (float*)d_out;

    unsigned short* qs = (unsigned short*)d_ws;              // [16384][512]
    unsigned short* kk = qs + (size_t)16384 * 512;           // [16384][512]
    unsigned short* vT = kk + (size_t)16384 * 512;           // [4][512][4096]

    qkv_gemm<<<dim3(128, 12), 256, 0, stream>>>(x, W, bias, qs, kk, vT);
    flash_attn<<<dim3(NSEQ / FA_BQ, BATCH), 512, 0, stream>>>(qs, kk, vT, out);
}